// Round 1
// baseline (498.596 us; speedup 1.0000x reference)
//
#include <hip/hip_runtime.h>

// RegimeAwareStudent: B=524288 tokens, ALL tensors fp32 (per reference), rid int32.
//   h  = relu(x @ fe_w1 + fe_b1)           [B,128]->[B,256]
//   f  = relu(h @ fe_w2 + fe_b2)           [B,256]->[B,128]
//   c  = concat(f, emb[rid])               [B,192]
//   eh = relu(c @ ew1[rid] + eb1[rid])     [B,192]->[B,256]
//   o  = eh @ ew2[rid] + eb2[rid]          [B,256]->[B,1]
// bf16 compute path (RNE at staging boundary), fp32 accumulate, fp32 out.
// R1 changes vs 535.6µs baseline:
//   * single LDS tile buffer [64][264] reused X->H->C (was sA+sH, 59.4KB ->
//     ~35KB) => 3-4 blocks/CU instead of 2; accumulators held across the
//     extra barriers that make the reuse safe.
//   * stage-3 B-fragments hoisted to registers once per regime (24 frags,
//     96 VGPR, statically indexed) instead of reloaded per 16-row m-tile.
//   * epilogue/staging f32->bf16 via v_cvt_pk_bf16_f32 (1 instr / 2 el)
//     instead of ~4-op software RNE.

typedef short short8 __attribute__((ext_vector_type(8)));
typedef float f32x4  __attribute__((ext_vector_type(4)));

#define MFMA16 __builtin_amdgcn_mfma_f32_16x16x32_bf16

constexpr int B_TOK  = 524288;
constexpr int TM     = 64;                 // tokens per tile
constexpr int NTILES = B_TOK / TM;         // 8192, exact

// packed-weight layout in d_ws (ushort element offsets)
constexpr size_t PW1_OFF   = 0;            // fe_w1: 4kt*16nt*64lane*8 = 32768 el
constexpr size_t PW2_OFF   = 32768;        // fe_w2: 8kt*8nt*64*8      = 32768 el
constexpr size_t PE1_OFF   = 65536;        // ew1:   3 * 6kt*16nt*64*8 = 147456 el
constexpr size_t PE1_PER_R = 49152;
// total ws = 212992 ushort = 425,984 bytes

static __device__ __forceinline__ ushort f2bf(float f) {  // RNE (repack only)
    union { float f; unsigned int i; } x; x.f = f;
    unsigned int i = x.i;
    i += 0x7fffu + ((i >> 16) & 1u);
    return (ushort)(i >> 16);
}

// HW packed f32->bf16 (RNE): D[15:0]=bf16(lo), D[31:16]=bf16(hi)
static __device__ __forceinline__ unsigned pk_bf16(float lo, float hi) {
    unsigned r;
    asm("v_cvt_pk_bf16_f32 %0, %1, %2" : "=v"(r) : "v"(lo), "v"(hi));
    return r;
}

static __device__ __forceinline__ short8 pack8(f32x4 f0, f32x4 f1) {
    union { unsigned u[4]; short8 s; } r;
    r.u[0] = pk_bf16(f0[0], f0[1]);
    r.u[1] = pk_bf16(f0[2], f0[3]);
    r.u[2] = pk_bf16(f1[0], f1[1]);
    r.u[3] = pk_bf16(f1[2], f1[3]);
    return r.s;
}

// ---- weight repack: fp32 -> bf16 MFMA B-fragment layout -------------------
// pw[frag=kt*NT+nt][lane][j] = bf16(W[kt*32 + (lane>>4)*8 + j][nt*16 + (lane&15)])
__global__ void repack_weights(const float* __restrict__ w1,
                               const float* __restrict__ w2,
                               const float* __restrict__ e1,
                               ushort* __restrict__ pw) {
    int t = blockIdx.x * 256 + threadIdx.x;       // 26624 threads total
    const float* src; int N, kt, nt; size_t dst;
    int lane = t & 63;
    if (t < 4096) {                                // fe_w1: K=128,N=256
        int frag = t >> 6; kt = frag >> 4; nt = frag & 15;
        src = w1; N = 256; dst = PW1_OFF + (size_t)t * 8;
    } else if (t < 8192) {                         // fe_w2: K=256,N=128
        int u = t - 4096; int frag = u >> 6; kt = frag >> 3; nt = frag & 7;
        src = w2; N = 128; dst = PW2_OFF + (size_t)u * 8;
    } else {                                       // ew1[r]: K=192,N=256
        int u = t - 8192; int reg = u / 6144; int v = u % 6144;
        int frag = v >> 6; kt = frag >> 4; nt = frag & 15;
        src = e1 + (size_t)reg * (192 * 256); N = 256;
        dst = PE1_OFF + (size_t)reg * PE1_PER_R + (size_t)v * 8;
    }
    int quad = lane >> 4, cc = lane & 15;
    int k0 = kt * 32 + quad * 8;
    int n  = nt * 16 + cc;
    short8 vv;
    #pragma unroll
    for (int j = 0; j < 8; ++j) vv[j] = (short)f2bf(src[(size_t)(k0 + j) * N + n]);
    *(short8*)(pw + dst) = vv;
}

// ---- fused main: 64 consecutive tokens, local regime sort, full MLP -------
// 256 threads = 4 waves; wave w owns an output-column quarter of each GEMM.
// One LDS buffer [64][264] reused X -> H -> C; accs live across the reuse
// barriers. Row stride 264 el = 528B: lane row-shift is 4 banks => b128
// reads are conflict-free/2-way only.
__global__ __launch_bounds__(256, 3) void fused_main(
    const float* __restrict__ x,
    const int*   __restrict__ rid,
    const ushort* __restrict__ pw,
    const float* __restrict__ fe_b1,
    const float* __restrict__ fe_b2,
    const float* __restrict__ emb,
    const float* __restrict__ eb1,
    const float* __restrict__ ew2,
    const float* __restrict__ eb2,
    float*       __restrict__ out) {
    __shared__ ushort sBuf[64 * 264];  // X tile, then H tile, then C tile
    __shared__ float  sRed[64 * 4];    // per-wave partials for final dot
    __shared__ ushort sPerm[64];       // local slot -> local token index
    __shared__ int    sBounds[4];      // {0, n0, n0+n1, 64} regime row ranges

    const int t    = threadIdx.x;
    const int w    = t >> 6;
    const int lane = t & 63;
    const int quad = lane >> 4;
    const int c    = lane & 15;
    const int ts   = blockIdx.x * TM;

    // ---- wave 0: local counting sort of 64 tokens by regime ----
    if (t < 64) {
        int myr = rid[ts + t];
        unsigned long long below = (1ull << t) - 1ull;
        int base = 0, slot = 0, bb1 = 0, bb2 = 0;
        #pragma unroll
        for (int r = 0; r < 3; ++r) {
            unsigned long long mask = __ballot(myr == r);
            if (myr == r) slot = base + __popcll(mask & below);
            base += __popcll(mask);
            if (r == 0) bb1 = base;
            if (r == 1) bb2 = base;
        }
        sPerm[slot] = (ushort)t;
        if (t == 0) { sBounds[0] = 0; sBounds[1] = bb1; sBounds[2] = bb2; sBounds[3] = 64; }
    }
    __syncthreads();

    const int b1 = sBounds[1], b2 = sBounds[2];

    // ---- gather X rows (fp32) -> bf16 into sBuf cols [0,128) via local perm ----
    #pragma unroll
    for (int it = 0; it < 4; ++it) {
        int chunk = it * 256 + t;
        int row = chunk >> 4, seg = chunk & 15;   // 8 floats per chunk
        int g = ts + sPerm[row];
        const float* xr = x + (size_t)g * 128 + seg * 8;
        f32x4 f0 = *(const f32x4*)xr;
        f32x4 f1 = *(const f32x4*)(xr + 4);
        *(short8*)(&sBuf[row * 264 + seg * 8]) = pack8(f0, f1);
    }
    __syncthreads();

    // ---- stage 1: H = relu(X @ W1 + b1); wave cols [w*64, w*64+64) ----
    f32x4 acc1[4][4] = {};
    #pragma unroll
    for (int kt = 0; kt < 4; ++kt) {
        short8 a[4], b[4];
        #pragma unroll
        for (int m = 0; m < 4; ++m)
            a[m] = *(const short8*)(&sBuf[(m * 16 + c) * 264 + kt * 32 + quad * 8]);
        #pragma unroll
        for (int nn = 0; nn < 4; ++nn)
            b[nn] = *(const short8*)(pw + PW1_OFF +
                    ((size_t)((kt * 16 + (w * 4 + nn)) * 64 + lane)) * 8);
        #pragma unroll
        for (int m = 0; m < 4; ++m)
            #pragma unroll
            for (int nn = 0; nn < 4; ++nn)
                acc1[m][nn] = MFMA16(a[m], b[nn], acc1[m][nn], 0, 0, 0);
    }
    __syncthreads();                 // all waves done reading X tile

    {   // epilogue: bias+relu, bf16-pack, write H into sBuf (stride 264)
        float b1v[4];
        #pragma unroll
        for (int nn = 0; nn < 4; ++nn) b1v[nn] = fe_b1[w * 64 + nn * 16 + c];
        #pragma unroll
        for (int m = 0; m < 4; ++m)
            #pragma unroll
            for (int nn = 0; nn < 4; ++nn) {
                int col = w * 64 + nn * 16 + c;
                int r0  = m * 16 + quad * 4;
                float v0 = fmaxf(acc1[m][nn][0] + b1v[nn], 0.0f);
                float v1 = fmaxf(acc1[m][nn][1] + b1v[nn], 0.0f);
                float v2 = fmaxf(acc1[m][nn][2] + b1v[nn], 0.0f);
                float v3 = fmaxf(acc1[m][nn][3] + b1v[nn], 0.0f);
                unsigned p01 = pk_bf16(v0, v1);
                unsigned p23 = pk_bf16(v2, v3);
                sBuf[(r0 + 0) * 264 + col] = (ushort)p01;
                sBuf[(r0 + 1) * 264 + col] = (ushort)(p01 >> 16);
                sBuf[(r0 + 2) * 264 + col] = (ushort)p23;
                sBuf[(r0 + 3) * 264 + col] = (ushort)(p23 >> 16);
            }
    }
    __syncthreads();

    // ---- stage 2: F = relu(H @ W2 + b2); wave cols [w*32, w*32+32) ----
    f32x4 acc2[4][2] = {};
    #pragma unroll
    for (int kt = 0; kt < 8; ++kt) {
        short8 a[4], b[2];
        #pragma unroll
        for (int m = 0; m < 4; ++m)
            a[m] = *(const short8*)(&sBuf[(m * 16 + c) * 264 + kt * 32 + quad * 8]);
        #pragma unroll
        for (int nn = 0; nn < 2; ++nn)
            b[nn] = *(const short8*)(pw + PW2_OFF +
                    ((size_t)((kt * 8 + (w * 2 + nn)) * 64 + lane)) * 8);
        #pragma unroll
        for (int m = 0; m < 4; ++m)
            #pragma unroll
            for (int nn = 0; nn < 2; ++nn)
                acc2[m][nn] = MFMA16(a[m], b[nn], acc2[m][nn], 0, 0, 0);
    }
    __syncthreads();                 // all waves done reading H tile

    {   // epilogue: write F into sBuf cols [0,128)
        float b2v[2];
        #pragma unroll
        for (int nn = 0; nn < 2; ++nn) b2v[nn] = fe_b2[w * 32 + nn * 16 + c];
        #pragma unroll
        for (int m = 0; m < 4; ++m)
            #pragma unroll
            for (int nn = 0; nn < 2; ++nn) {
                int col = w * 32 + nn * 16 + c;
                int r0  = m * 16 + quad * 4;
                float v0 = fmaxf(acc2[m][nn][0] + b2v[nn], 0.0f);
                float v1 = fmaxf(acc2[m][nn][1] + b2v[nn], 0.0f);
                float v2 = fmaxf(acc2[m][nn][2] + b2v[nn], 0.0f);
                float v3 = fmaxf(acc2[m][nn][3] + b2v[nn], 0.0f);
                unsigned p01 = pk_bf16(v0, v1);
                unsigned p23 = pk_bf16(v2, v3);
                sBuf[(r0 + 0) * 264 + col] = (ushort)p01;
                sBuf[(r0 + 1) * 264 + col] = (ushort)(p01 >> 16);
                sBuf[(r0 + 2) * 264 + col] = (ushort)p23;
                sBuf[(r0 + 3) * 264 + col] = (ushort)(p23 >> 16);
            }
    }
    // append per-row regime embedding (fp32 -> bf16) to C tile cols [128,192)
    #pragma unroll
    for (int it = 0; it < 2; ++it) {
        int chunk = it * 256 + t;
        int row = chunk >> 3, seg = chunk & 7;    // 8 floats per chunk
        int rr = (row >= b1) + (row >= b2);       // sorted rows -> row regime
        const float* ep = emb + rr * 64 + seg * 8;
        f32x4 f0 = *(const f32x4*)ep;
        f32x4 f1 = *(const f32x4*)(ep + 4);
        *(short8*)(&sBuf[row * 264 + 128 + seg * 8]) = pack8(f0, f1);
    }
    __syncthreads();

    // ---- stage 3: per regime present, over intersecting 16-row m-tiles ----
    // B-fragments hoisted to registers ONCE per regime (24 frags = 96 VGPR,
    // all indices compile-time) and reused across m-tiles.
    for (int r = 0; r < 3; ++r) {
        int lo = __builtin_amdgcn_readfirstlane(sBounds[r]);
        int hi = __builtin_amdgcn_readfirstlane(sBounds[r + 1]);
        if (lo >= hi) continue;               // block-uniform
        const ushort* pe = pw + PE1_OFF + (size_t)r * PE1_PER_R;
        short8 bf[6][4];
        #pragma unroll
        for (int kt = 0; kt < 6; ++kt)
            #pragma unroll
            for (int nn = 0; nn < 4; ++nn)
                bf[kt][nn] = *(const short8*)(pe +
                        ((size_t)((kt * 16 + (w * 4 + nn)) * 64 + lane)) * 8);
        float eb1v[4], w2v[4];
        #pragma unroll
        for (int nn = 0; nn < 4; ++nn) {
            int col = w * 64 + nn * 16 + c;
            eb1v[nn] = eb1[r * 256 + col];
            w2v[nn]  = ew2[r * 256 + col];
        }
        int mlo = lo >> 4, mhi = (hi - 1) >> 4;
        for (int m = mlo; m <= mhi; ++m) {    // block-uniform
            f32x4 acc[4] = {};
            #pragma unroll
            for (int kt = 0; kt < 6; ++kt) {
                short8 a = *(const short8*)(&sBuf[(m * 16 + c) * 264 + kt * 32 + quad * 8]);
                #pragma unroll
                for (int nn = 0; nn < 4; ++nn)
                    acc[nn] = MFMA16(a, bf[kt][nn], acc[nn], 0, 0, 0);
            }
            float s[4] = {0.f, 0.f, 0.f, 0.f};
            #pragma unroll
            for (int nn = 0; nn < 4; ++nn)
                #pragma unroll
                for (int i = 0; i < 4; ++i)
                    s[i] += fmaxf(acc[nn][i] + eb1v[nn], 0.0f) * w2v[nn];
            #pragma unroll
            for (int i = 0; i < 4; ++i) {     // reduce over 16 cols (lane bits 0..3)
                s[i] += __shfl_xor(s[i], 1);
                s[i] += __shfl_xor(s[i], 2);
                s[i] += __shfl_xor(s[i], 4);
                s[i] += __shfl_xor(s[i], 8);
            }
            if (c == 0) {
                #pragma unroll
                for (int i = 0; i < 4; ++i) {
                    int row = m * 16 + quad * 4 + i;
                    if (row >= lo && row < hi) sRed[row * 4 + w] = s[i];
                }
            }
        }
    }
    __syncthreads();

    // ---- final: sum 4 wave-partials + eb2[regime], scatter fp32 out ----
    if (t < 64) {
        int rr = (t >= b1) + (t >= b2);
        f32x4 rv = *(const f32x4*)(&sRed[t * 4]);
        float sum = rv[0] + rv[1] + rv[2] + rv[3] + eb2[rr];
        out[ts + sPerm[t]] = sum;
    }
}

extern "C" void kernel_launch(void* const* d_in, const int* in_sizes, int n_in,
                              void* d_out, int out_size, void* d_ws, size_t ws_size,
                              hipStream_t stream) {
    const float* x     = (const float*)d_in[0];
    const int*   rid   = (const int*)d_in[1];
    const float* fe_w1 = (const float*)d_in[2];
    const float* fe_b1 = (const float*)d_in[3];
    const float* fe_w2 = (const float*)d_in[4];
    const float* fe_b2 = (const float*)d_in[5];
    const float* emb   = (const float*)d_in[6];
    const float* ew1   = (const float*)d_in[7];
    const float* eb1   = (const float*)d_in[8];
    const float* ew2   = (const float*)d_in[9];
    const float* eb2   = (const float*)d_in[10];
    float* out = (float*)d_out;
    ushort* pw = (ushort*)d_ws;   // 425,984 bytes used

    hipLaunchKernelGGL(repack_weights, dim3(104), dim3(256), 0, stream,
                       fe_w1, fe_w2, ew1, pw);
    hipLaunchKernelGGL(fused_main, dim3(NTILES), dim3(256), 0, stream,
                       x, rid, pw, fe_b1, fe_b2, emb, eb1, ew2, eb2, out);
}